// Round 2
// baseline (672.706 us; speedup 1.0000x reference)
//
#include <hip/hip_runtime.h>
#include <hip/hip_cooperative_groups.h>

namespace cg = cooperative_groups;

constexpr int Bn  = 8;
constexpr int Ln  = 2048;
constexpr int En  = 4096;
constexpr int TDn = 768;   // TOKEN_DIM
constexpr int EDn = 256;   // EDGE_DIM
constexpr int Hn  = 128;   // HIDDEN

// ws layout (float offsets)
constexpr int OFF_V1  = 0;        // 768    : W_fc[:768] @ a1
constexpr int OFF_T   = 1024;     // B*768  : weighted token sums (atomic)
constexpr int OFF_S   = 8192;     // B*L    : raw scores
constexpr int OFF_ROW = 24576;    // B*128  : per-batch output row
constexpr int OFF_EP  = 32768;    // 2048*256 : per-wave edge column partials
// total ~2.2 MB << ws_size

__global__ __launch_bounds__(256, 4)
void k_fused(const float* __restrict__ token, const float* __restrict__ edge,
             const float* __restrict__ W, const float* __restrict__ a,
             float* __restrict__ ws, float4* __restrict__ out) {
    cg::grid_group grid = cg::this_grid();
    const int bid  = blockIdx.x;     // 0..1023
    const int tid  = threadIdx.x;    // 0..255
    const int wv   = tid >> 6;
    const int lane = tid & 63;

    __shared__ float4 s_v1[TDn / 4]; // 3 KB
    __shared__ float  s_red[256];
    __shared__ float  s_es[EDn];
    __shared__ float  s_p[16];

    // ---- P0: v1[d] = W[d,:128] . a1 — one wave per d ----------------------
    {
        int gw = bid * 4 + wv;
        if (gw < TDn) {
            float acc = W[gw * Hn + lane]      * a[lane]
                      + W[gw * Hn + 64 + lane] * a[64 + lane];
            #pragma unroll
            for (int off = 32; off > 0; off >>= 1)
                acc += __shfl_down(acc, off, 64);
            if (lane == 0) ws[OFF_V1 + gw] = acc;
        }
    }
    grid.sync();

    // ---- P1: edge partials (blocks 0..511) || scores (blocks 512..1023) ---
    if (bid < 512) {
        int b = bid >> 6, chunk = bid & 63;    // 64 rows/block, 16/wave
        const float4* e4 = (const float4*)edge
                         + ((size_t)(b * En + chunk * 64 + wv * 16)) * (EDn / 4);
        float4 acc = {0.f, 0.f, 0.f, 0.f};
        #pragma unroll 4
        for (int k = 0; k < 16; ++k) {
            float4 v = e4[(size_t)k * (EDn / 4) + lane];
            acc.x += v.x; acc.y += v.y; acc.z += v.z; acc.w += v.w;
        }
        ((float4*)(ws + OFF_EP))[(bid * 4 + wv) * 64 + lane] = acc;
        if (bid < 24) ws[OFF_T + bid * 256 + tid] = 0.f;   // zero t-accumulator
    } else {
        if (tid < TDn / 4) s_v1[tid] = ((const float4*)(ws + OFF_V1))[tid];
        __syncthreads();
        int w = (bid - 512) * 4 + wv;          // 0..2047, 8 rows/wave
        for (int i = 0; i < 8; ++i) {
            int row = w * 8 + i;
            const float4* t4 = (const float4*)token + (size_t)row * (TDn / 4);
            float acc = 0.f;
            #pragma unroll
            for (int j = 0; j < 3; ++j) {
                float4 t = t4[lane + 64 * j];
                float4 v = s_v1[lane + 64 * j];
                acc += t.x * v.x + t.y * v.y + t.z * v.z + t.w * v.w;
            }
            #pragma unroll
            for (int off = 32; off > 0; off >>= 1)
                acc += __shfl_down(acc, off, 64);
            if (lane == 0) ws[OFF_S + row] = acc;
        }
    }
    grid.sync();

    // ---- P2: per-block softmax normalization + weighted token sums --------
    {
        int b = bid >> 7, chunk = bid & 127;   // 16 rows per block
        const float* sb = ws + OFF_S + b * Ln;
        float v[8];
        float m = -1e30f;
        #pragma unroll
        for (int k = 0; k < 8; ++k) { v[k] = sb[tid + 256 * k]; m = fmaxf(m, v[k]); }
        s_red[tid] = m; __syncthreads();
        for (int o = 128; o > 0; o >>= 1) {
            if (tid < o) s_red[tid] = fmaxf(s_red[tid], s_red[tid + o]);
            __syncthreads();
        }
        m = s_red[0]; __syncthreads();
        float sum = 0.f;
        #pragma unroll
        for (int k = 0; k < 8; ++k) sum += expf(v[k] - m);
        s_red[tid] = sum; __syncthreads();
        for (int o = 128; o > 0; o >>= 1) {
            if (tid < o) s_red[tid] += s_red[tid + o];
            __syncthreads();
        }
        float inv = 1.0f / s_red[0];
        if (tid < 16) s_p[tid] = expf(sb[chunk * 16 + tid] - m) * inv;
        __syncthreads();

        const float* tok = token + ((size_t)(b * Ln + chunk * 16)) * TDn;
        float a0 = 0.f, a1 = 0.f, a2 = 0.f;
        #pragma unroll 4
        for (int l = 0; l < 16; ++l) {
            float wgt = s_p[l];
            const float* r = tok + (size_t)l * TDn;
            a0 += wgt * r[tid];
            a1 += wgt * r[tid + 256];
            a2 += wgt * r[tid + 512];
        }
        atomicAdd(&ws[OFF_T + b * TDn + tid],       a0);
        atomicAdd(&ws[OFF_T + b * TDn + tid + 256], a1);
        atomicAdd(&ws[OFF_T + b * TDn + tid + 512], a2);
    }
    grid.sync();

    // ---- P3: row[b,h] = t[b,:]·W[:768,h] + (edge_mean[b,:])·W[768:,h] -----
    if (bid < Bn) {
        int b = bid;
        float e = 0.f;
        for (int k = 0; k < 256; ++k)
            e += ws[OFF_EP + (b * 256 + k) * EDn + tid];
        s_es[tid] = e * (1.0f / En);
        __syncthreads();
        int h = tid & 127, half = tid >> 7;
        const float* tb = ws + OFF_T + b * TDn;
        float acc = 0.f;
        for (int d = half * 512; d < half * 512 + 512; ++d) {
            float tv = (d < TDn) ? tb[d] : s_es[d - TDn];
            acc += tv * W[d * Hn + h];
        }
        s_red[tid] = acc; __syncthreads();
        if (tid < 128)
            ws[OFF_ROW + b * Hn + tid] = s_red[tid] + s_red[tid + 128];
    }
    grid.sync();

    // ---- P4: broadcast row to out[b,i,:] ----------------------------------
    {
        const float4* row4 = (const float4*)(ws + OFF_ROW);
        int g = bid * 256 + tid;
        #pragma unroll
        for (int k = 0; k < 2; ++k) {
            int idx = g + k * 262144;          // 0 .. 524287
            int b = idx >> 16;                 // / (L*H/4)
            int q = idx & 31;                  // & (H/4 - 1)
            out[idx] = row4[b * 32 + q];
        }
    }
}

extern "C" void kernel_launch(void* const* d_in, const int* in_sizes, int n_in,
                              void* d_out, int out_size, void* d_ws, size_t ws_size,
                              hipStream_t stream) {
    const float* token = (const float*)d_in[0];
    const float* edge  = (const float*)d_in[1];
    const float* W     = (const float*)d_in[2];
    const float* a     = (const float*)d_in[3];
    // d_in[4] (b_attn) cancels in the softmax — unused.
    float*  ws  = (float*)d_ws;
    float4* out = (float4*)d_out;

    void* args[] = {(void*)&token, (void*)&edge, (void*)&W, (void*)&a,
                    (void*)&ws, (void*)&out};
    hipLaunchCooperativeKernel((const void*)k_fused, dim3(1024), dim3(256),
                               args, 0, stream);
}

// Round 3
// 154.033 us; speedup vs baseline: 4.3673x; 4.3673x over previous
//
#include <hip/hip_runtime.h>

constexpr int Bn  = 8;
constexpr int Ln  = 2048;
constexpr int En  = 4096;
constexpr int TDn = 768;   // TOKEN_DIM
constexpr int EDn = 256;   // EDGE_DIM
constexpr int Hn  = 128;   // HIDDEN

// ws layout (float offsets)
constexpr int OFF_V1    = 0;                       // 768
constexpr int OFF_S     = 1024;                    // B*L = 16384
constexpr int OFF_EPART = 17408;                   // 1024 blocks * 256 = 262144
constexpr int OFF_TPART = 279552;                  // 1024 blocks * 768 = 786432
constexpr int OFF_T     = 1065984;                 // B*768 = 6144
constexpr int OFF_ES    = 1072128;                 // B*256 = 2048
constexpr int OFF_ROW   = 1074176;                 // B*128 = 1024
// total ~4.1 MB

// ---- kA: v1 (blocks 0..2)  +  edge block partials (blocks 3..1026) --------
__global__ __launch_bounds__(256)
void kA(const float* __restrict__ edge, const float* __restrict__ W,
        const float* __restrict__ a, float* __restrict__ ws) {
    const int tid = threadIdx.x, wv = tid >> 6, q = tid & 63;
    __shared__ float  s_a1[Hn];
    __shared__ float4 s_red[4][64];

    if (blockIdx.x < 3) {
        if (tid < Hn) s_a1[tid] = a[tid];
        __syncthreads();
        int d = blockIdx.x * 256 + tid;            // 0..767
        const float* w = W + d * Hn;
        float acc = 0.f;
        #pragma unroll 8
        for (int h = 0; h < Hn; ++h) acc += w[h] * s_a1[h];
        ws[OFF_V1 + d] = acc;
        return;
    }
    int eb = blockIdx.x - 3;                       // 0..1023
    int b = eb >> 7, chunk = eb & 127;             // 32 rows per block
    const float4* e4 = (const float4*)edge
                     + ((size_t)(b * En + chunk * 32 + wv * 8)) * (EDn / 4) + q;
    float4 acc = {0.f, 0.f, 0.f, 0.f};
    #pragma unroll
    for (int i = 0; i < 8; ++i) {
        float4 v = e4[(size_t)i * (EDn / 4)];
        acc.x += v.x; acc.y += v.y; acc.z += v.z; acc.w += v.w;
    }
    s_red[wv][q] = acc;
    __syncthreads();
    if (tid < 64) {
        float4 r0 = s_red[0][tid], r1 = s_red[1][tid],
               r2 = s_red[2][tid], r3 = s_red[3][tid];
        float4 s = {r0.x + r1.x + r2.x + r3.x, r0.y + r1.y + r2.y + r3.y,
                    r0.z + r1.z + r2.z + r3.z, r0.w + r1.w + r2.w + r3.w};
        ((float4*)(ws + OFF_EPART))[eb * 64 + tid] = s;
    }
}

// ---- kB: s[b,l] = token[b,l,:] . v1 — one wave per row --------------------
__global__ __launch_bounds__(256)
void kB(const float* __restrict__ token, float* __restrict__ ws) {
    __shared__ float4 s_v1[TDn / 4];
    const int tid = threadIdx.x, wv = tid >> 6, lane = tid & 63;
    if (tid < TDn / 4) s_v1[tid] = ((const float4*)(ws + OFF_V1))[tid];
    __syncthreads();
    int row = blockIdx.x * 4 + wv;                 // 0 .. B*L-1
    const float4* t4 = (const float4*)token + (size_t)row * (TDn / 4);
    float acc = 0.f;
    #pragma unroll
    for (int j = 0; j < 3; ++j) {
        float4 t = t4[lane + 64 * j];
        float4 v = s_v1[lane + 64 * j];
        acc += t.x * v.x + t.y * v.y + t.z * v.z + t.w * v.w;
    }
    #pragma unroll
    for (int off = 32; off > 0; off >>= 1)
        acc += __shfl_down(acc, off, 64);
    if (lane == 0) ws[OFF_S + row] = acc;
}

// ---- kC: in-place softmax over L per batch --------------------------------
__global__ __launch_bounds__(256)
void kC(float* __restrict__ ws) {
    float* s = ws + OFF_S + blockIdx.x * Ln;
    __shared__ float red[256];
    int tid = threadIdx.x;
    float v[8];
    float m = -1e30f;
    #pragma unroll
    for (int k = 0; k < 8; ++k) { v[k] = s[tid + 256 * k]; m = fmaxf(m, v[k]); }
    red[tid] = m; __syncthreads();
    for (int o = 128; o > 0; o >>= 1) {
        if (tid < o) red[tid] = fmaxf(red[tid], red[tid + o]);
        __syncthreads();
    }
    m = red[0]; __syncthreads();
    float sum = 0.f;
    #pragma unroll
    for (int k = 0; k < 8; ++k) { v[k] = expf(v[k] - m); sum += v[k]; }
    red[tid] = sum; __syncthreads();
    for (int o = 128; o > 0; o >>= 1) {
        if (tid < o) red[tid] += red[tid + o];
        __syncthreads();
    }
    float inv = 1.0f / red[0];
    #pragma unroll
    for (int k = 0; k < 8; ++k) s[tid + 256 * k] = v[k] * inv;
}

// ---- kD: weighted token block partials. 1024 blocks x 192 threads ---------
__global__ __launch_bounds__(192)
void kD(const float* __restrict__ token, float* __restrict__ ws) {
    __shared__ float s_p[16];
    const int tid = threadIdx.x;                   // 0..191 (float4 column)
    int b = blockIdx.x >> 7, chunk = blockIdx.x & 127;  // 16 rows per block
    if (tid < 16) s_p[tid] = ws[OFF_S + b * Ln + chunk * 16 + tid];
    __syncthreads();
    const float4* t4 = (const float4*)token
                     + ((size_t)(b * Ln + chunk * 16)) * (TDn / 4) + tid;
    float4 acc = {0.f, 0.f, 0.f, 0.f};
    #pragma unroll 4
    for (int l = 0; l < 16; ++l) {
        float4 v = t4[(size_t)l * (TDn / 4)];
        float w = s_p[l];
        acc.x += w * v.x; acc.y += w * v.y; acc.z += w * v.z; acc.w += w * v.w;
    }
    ((float4*)(ws + OFF_TPART))[blockIdx.x * (TDn / 4) + tid] = acc;
}

// ---- kE1: combine partials. blocks 0..23 -> t[b,d]; 24..31 -> es[b,c] -----
__global__ __launch_bounds__(256)
void kE1(float* __restrict__ ws) {
    int tid = threadIdx.x;
    if (blockIdx.x < 24) {
        int b = blockIdx.x / 3, part = blockIdx.x % 3;
        int d = part * 256 + tid;                  // 0..767
        const float* p = ws + OFF_TPART + (size_t)(b * 128) * TDn + d;
        float acc = 0.f;
        #pragma unroll 4
        for (int ch = 0; ch < 128; ++ch) acc += p[(size_t)ch * TDn];
        ws[OFF_T + b * TDn + d] = acc;
    } else {
        int b = blockIdx.x - 24;
        const float* p = ws + OFF_EPART + (size_t)(b * 128) * EDn + tid;
        float acc = 0.f;
        #pragma unroll 4
        for (int ch = 0; ch < 128; ++ch) acc += p[(size_t)ch * EDn];
        ws[OFF_ES + b * EDn + tid] = acc * (1.0f / En);
    }
}

// ---- kE2: row[b,h] = t[b,:].W[:768,h] + es[b,:].W[768:,h] -----------------
__global__ __launch_bounds__(1024)
void kE2(const float* __restrict__ W, float* __restrict__ ws) {
    __shared__ float s_c[1024];
    __shared__ float s_red[1024];
    int b = blockIdx.x, tid = threadIdx.x;
    s_c[tid] = (tid < TDn) ? ws[OFF_T + b * TDn + tid]
                           : ws[OFF_ES + b * EDn + (tid - TDn)];
    __syncthreads();
    int h = tid & 127, dg = tid >> 7;              // 8 groups of 128 d
    const float* w = W + (dg * 128) * Hn + h;
    float acc = 0.f;
    #pragma unroll 4
    for (int i = 0; i < 128; ++i)
        acc += s_c[dg * 128 + i] * w[i * Hn];
    s_red[tid] = acc;
    __syncthreads();
    if (tid < 128) {
        float r = 0.f;
        #pragma unroll
        for (int g = 0; g < 8; ++g) r += s_red[g * 128 + tid];
        ws[OFF_ROW + b * Hn + tid] = r;
    }
}

// ---- kF: broadcast row to out[b,i,:] --------------------------------------
__global__ __launch_bounds__(256)
void kF(const float* __restrict__ ws, float4* __restrict__ out) {
    int idx = blockIdx.x * blockDim.x + threadIdx.x;  // 0 .. 524287
    int b = idx >> 16;                                // / (L*H/4)
    int q = idx & (Hn / 4 - 1);
    out[idx] = ((const float4*)(ws + OFF_ROW))[b * (Hn / 4) + q];
}

extern "C" void kernel_launch(void* const* d_in, const int* in_sizes, int n_in,
                              void* d_out, int out_size, void* d_ws, size_t ws_size,
                              hipStream_t stream) {
    const float* token = (const float*)d_in[0];
    const float* edge  = (const float*)d_in[1];
    const float* W     = (const float*)d_in[2];
    const float* a     = (const float*)d_in[3];
    // d_in[4] (b_attn) cancels in the softmax — unused.
    float* ws  = (float*)d_ws;
    float4* out = (float4*)d_out;

    kA <<<1027,          256, 0, stream>>>(edge, W, a, ws);
    kB <<<Bn * Ln / 4,   256, 0, stream>>>(token, ws);
    kC <<<Bn,            256, 0, stream>>>(ws);
    kD <<<1024,          192, 0, stream>>>(token, ws);
    kE1<<<32,            256, 0, stream>>>(ws);
    kE2<<<Bn,           1024, 0, stream>>>(W, ws);
    kF <<<2048,          256, 0, stream>>>(ws, out);
}